// Round 14
// baseline (180.091 us; speedup 1.0000x reference)
//
#include <hip/hip_runtime.h>
#include <hip/hip_bf16.h>

// Problem constants
#define BATCH 16
#define IN_C 3
#define Q_C 8
#define V_C 16
#define HH 224
#define WW 224
#define KK 7

// Padded layouts
#define XPH 230   // stored row = orig row + 3
#define XPW 232
#define QPH 118
#define QPW 120
#define QP_PLANE (QPH*QPW)            // 14160 per (qc)
#define QP_QSTRIDE (Q_C*QP_PLANE)     // 113280 per (b,ic)

// pT2: [b][ci][mb=0..201][kc=0..111][8], element m = 8*mb+j, m=row*7+dx,
// value = x[b,ci,row-3, 2*kc+dx-3]; m >= 1610 zero-padded.
#define PT_MB    202
#define PT2_CHUNKS (BATCH*IN_C*PT_MB*112)      // 1,085,952 16B-chunks
#define PT2_N    ((size_t)PT2_CHUNKS*8)        // 8,687,616 bf16

// Region sizes (elements)
#define PLANES_N (BATCH*7*IN_C*XPH*QPW)        // 9,273,600 bf16
#define VPAD_N   (BATCH*V_C*QPH*QPW)           // 3,624,960 f32
#define QPADS_N  (BATCH*IN_C*QP_QSTRIDE)       // 5,437,440 bf16
#define D_N      (BATCH*160*384)               // [b][n=160][m'=384]
#define SPLITS   16
#define DPART_N  ((size_t)SPLITS*D_N)          // bf16 partials, 31.5 MB
#define OUT_N    (BATCH*IN_C*58*58)
#define AW_N     (4*48*192)                    // 4 phase-shifted weight mats

// WZ tail-work partition (fused into kXT)
#define ZQ_CHUNKS (BATCH*IN_C*Q_C*6*15)        // 34560 uint4 (q planes, 6 border rows)
#define ZV_CHUNKS (BATCH*V_C*6*30)             // 46080 uint4 (v planes, 6 border rows)
#define WZ_TOTAL  (AW_N + ZQ_CHUNKS + ZV_CHUNKS)   // 117504
#define XT_BLOCKS (BATCH*IN_C*29)              // 1392
#define WZ_BLOCKS ((WZ_TOTAL + 255) / 256)     // 459

typedef __attribute__((ext_vector_type(8))) short bf16x8;
typedef __attribute__((ext_vector_type(4))) float f32x4;
typedef __attribute__((ext_vector_type(4))) unsigned short u16x4;
typedef __attribute__((ext_vector_type(4))) unsigned int u32x4;   // native vec for nontemporal builtins

struct __attribute__((packed, aligned(4))) uint4_a4 { uint4 v; };
struct __attribute__((packed, aligned(4))) float4_a4 { float4 v; };

static __device__ inline unsigned short f2b(float f) {
    __hip_bfloat16 h = __float2bfloat16(f);
    return *reinterpret_cast<unsigned short*>(&h);
}
static __device__ inline float b2f(unsigned short u) {
    unsigned int v = ((unsigned int)u) << 16;
    return __builtin_bit_cast(float, v);
}
static __device__ inline bf16x8 ld16(const unsigned short* p) {
    return __builtin_bit_cast(bf16x8, *(const uint4*)p);
}

// ---------------- Kernel XT: fused planes + pT2 builder + WZ tail -----------
// planes written NONTEMPORAL: read exactly once by kC (no L2 reuse), so keep
// its 18.5 MB of dirty lines out of L2 / out of kC's writeback window.
__global__ __launch_bounds__(256) void kXT(const float* __restrict__ x,
                                           unsigned short* __restrict__ planes,
                                           unsigned short* __restrict__ pT2,
                                           const float* __restrict__ Wq,
                                           const float* __restrict__ Wv,
                                           unsigned short* __restrict__ Aw2,
                                           unsigned short* __restrict__ qpadS,
                                           float* __restrict__ vpad) {
    int blk = blockIdx.x;
    int tid = threadIdx.x;

    if (blk >= XT_BLOCKS) {
        // ---- WZ tail work ----
        int idx = (blk - XT_BLOCKS) * 256 + tid;
        if (idx >= WZ_TOTAL) return;
        if (idx < AW_N) {
            int n = idx % 192;
            int t3 = idx / 192;
            int ch = t3 % 48;
            int p4 = t3 / 48;
            int ci = n / 64;
            int t  = (n % 64) - 2 * p4;
            float v = 0.0f;
            if (ch < 40 && t >= 0 && t < 49) {
                int k = ci * 49 + t;
                v = (ch < 24) ? Wq[(size_t)ch * 147 + k] : Wv[(size_t)(ch - 24) * 147 + k];
            }
            Aw2[idx] = f2b(v);
            return;
        }
        uint4 z = uint4{0, 0, 0, 0};
        int j = idx - AW_N;
        if (j < ZQ_CHUNKS) {
            int ko = j % 15;
            int t2 = j / 15;
            int r6 = t2 % 6;
            int plane = t2 / 6;
            int row = (r6 < 3) ? r6 : (112 + r6);   // 0,1,2,115,116,117
            *(uint4*)(qpadS + (size_t)plane * QP_PLANE + (size_t)row * QPW + 8 * ko) = z;
        } else {
            int j2 = j - ZQ_CHUNKS;
            int ko = j2 % 30;
            int t2 = j2 / 30;
            int r6 = t2 % 6;
            int plane = t2 / 6;
            int row = (r6 < 3) ? r6 : (112 + r6);
            *(uint4*)((char*)(vpad + (size_t)plane * QP_PLANE + (size_t)row * QPW) + 16 * ko) = z;
        }
        return;
    }

    // ---- stripe work: blk = b*87 + ci*29 + r0 ----
    int r0 = blk % 29;
    int t0 = blk / 29;
    int ci = t0 % IN_C;
    int b  = t0 / IN_C;

    __shared__ unsigned short xl[8][240];   // LDS col c = orig col c-3

    const float* xb = x + (size_t)(b * IN_C + ci) * (HH * WW);
    for (int idx = tid; idx < 8 * 240; idx += 256) {
        int row8 = idx / 240, c = idx % 240;
        int r = 8 * r0 + row8 - 3;          // orig row
        int cc = c - 3;                     // orig col
        float val = 0.0f;
        if (r >= 0 && r < HH && cc >= 0 && cc < WW)
            val = xb[(size_t)r * WW + cc];
        xl[row8][c] = f2b(val);
    }
    __syncthreads();

    // Phase A: planes[b][dx][ci][prow][k], FULL rows: 15 uint4 chunks (NT)
    for (int t2 = tid; t2 < 840; t2 += 256) {
        int ko = t2 % 15;
        int t3 = t2 / 15;
        int row8 = t3 % 8;
        int dx = t3 / 8;
        int prow = 8 * r0 + row8;
        if (prow >= XPH) continue;
        unsigned short pk[8];
        if (ko < 14) {
            #pragma unroll
            for (int j = 0; j < 8; ++j)
                pk[j] = xl[row8][16 * ko + 2 * j + dx];
        } else {
            #pragma unroll
            for (int j = 0; j < 8; ++j) pk[j] = 0;   // pad cols [112,120)
        }
        unsigned short* dst = planes
            + ((size_t)((b * 7 + dx) * IN_C + ci) * XPH + prow) * QPW + 8 * ko;
        __builtin_nontemporal_store(*(const u32x4*)pk, (u32x4*)dst);
    }

    // Phase B: pT2[b][ci][mb][kc][8] (regular: kA has L2 reuse on pT2)
    for (int t2 = tid; t2 < 784; t2 += 256) {
        int kc  = t2 % 112;
        int mbr = t2 / 112;
        int mb = 7 * r0 + mbr;
        if (mb >= PT_MB) continue;
        unsigned short pk[8];
        #pragma unroll
        for (int j = 0; j < 8; ++j) {
            int mrel = 8 * mbr + j;          // in [0,56): row8 = mrel/7
            int row8 = mrel / 7;
            int dxm  = mrel - 7 * row8;
            pk[j] = xl[row8][2 * kc + dxm];  // rows >=230 already zero in LDS
        }
        unsigned short* dst = pT2 + ((size_t)((b * IN_C + ci) * PT_MB + mb) * 112 + kc) * 8;
        *(uint4*)dst = *(const uint4*)pk;
    }
}

// ---------------- Kernel A: MFMA q+v conv, LDS-staged full-row epilogue -----
// vpad written NONTEMPORAL: read only by kO (4 kernels later) -> keep its
// 14.5 MB out of kC's writeback window. qpadS regular (kC reuses via L2).
__global__ __launch_bounds__(256) void kA(const unsigned short* __restrict__ pT2,
                                          const unsigned short* __restrict__ Aw2,
                                          const float* __restrict__ bq,
                                          const float* __restrict__ bv,
                                          unsigned short* __restrict__ qpadS,
                                          float* __restrict__ vpad) {
    int g = blockIdx.x;                 // 448 blocks; XCD swizzle: b tracks g&7
    int r8 = g & 7, q8 = g >> 3;
    int b  = r8 + 8 * (q8 / 28);
    int yq = q8 % 28;
    int w  = threadIdx.x >> 6;
    int yo = yq * 4 + w;                // [0,112)
    int lane = threadIdx.x & 63;
    int cl = lane & 15, kq = lane >> 4;

    __shared__ unsigned short qs[4][24][120];   // per-wave q rows (full 120)
    __shared__ float          vs[4][16][120];   // per-wave v rows

    int m14 = 14 * yo;
    int p4  = (m14 >> 1) & 3;           // (14yo mod 8)/2
    int ms8 = m14 >> 3;                 // aligned m-block start

    const unsigned short* AwP = Aw2 + (size_t)p4 * (48 * 192);
    bf16x8 af[3][6];
    #pragma unroll
    for (int mt = 0; mt < 3; ++mt)
        #pragma unroll
        for (int s = 0; s < 6; ++s)
            af[mt][s] = ld16(AwP + (size_t)(mt * 16 + cl) * 192 + s * 32 + kq * 8);

    f32x4 acc[3][7];
    #pragma unroll
    for (int mt = 0; mt < 3; ++mt)
        #pragma unroll
        for (int nt = 0; nt < 7; ++nt)
            acc[mt][nt] = f32x4{0.f, 0.f, 0.f, 0.f};

    #pragma unroll
    for (int s = 0; s < 6; ++s) {
        int ci = s >> 1;
        int mb = ms8 + kq + 4 * (s & 1);
        const unsigned short* bp = pT2
            + ((size_t)((b * IN_C + ci) * PT_MB + mb) * 112) * 8;
        bf16x8 bfr[7];
        #pragma unroll
        for (int nt = 0; nt < 7; ++nt)
            bfr[nt] = ld16(bp + (size_t)(nt * 16 + cl) * 8);
        #pragma unroll
        for (int nt = 0; nt < 7; ++nt)
            #pragma unroll
            for (int mt = 0; mt < 3; ++mt)
                acc[mt][nt] = __builtin_amdgcn_mfma_f32_16x16x32_bf16(af[mt][s], bfr[nt], acc[mt][nt], 0, 0, 0);
    }

    float bias[3][4];
    #pragma unroll
    for (int mt = 0; mt < 3; ++mt)
        #pragma unroll
        for (int r = 0; r < 4; ++r) {
            int ch = mt * 16 + kq * 4 + r;
            bias[mt][r] = (ch < 24) ? bq[ch] : (ch < 40 ? bv[ch - 24] : 0.0f);
        }

    // zero the col pads (0..2, 115..119) of this wave's LDS rows
    for (int i = lane; i < 24 * 8; i += 64) {
        int ch = i / 8, c = i % 8;
        qs[w][ch][(c < 3) ? c : (112 + c)] = 0;
    }
    for (int i = lane; i < 16 * 8; i += 64) {
        int ch = i / 8, c = i % 8;
        vs[w][ch][(c < 3) ? c : (112 + c)] = 0.0f;
    }

    // scatter acc -> LDS rows
    #pragma unroll
    for (int mt = 0; mt < 3; ++mt) {
        #pragma unroll
        for (int nt = 0; nt < 7; ++nt) {
            int kc = nt * 16 + cl;
            #pragma unroll
            for (int r = 0; r < 4; ++r) {
                int ch = mt * 16 + kq * 4 + r;
                float val = acc[mt][nt][r] + bias[mt][r];
                if (ch < 24) qs[w][ch][3 + kc] = f2b(val);
                else if (ch < 40) vs[w][ch - 24][3 + kc] = val;
            }
        }
    }
    __syncthreads();

    // coalesced full-row stores
    int orow = yo + 3;
    for (int i = lane; i < 24 * 15; i += 64) {       // q: 24 rows x 15 uint4
        int ch = i / 15, ko = i % 15;
        int icq = ch >> 3, qc = ch & 7;
        *(uint4*)(qpadS + (size_t)((b * 3 + icq) * 8 + qc) * QP_PLANE
                  + (size_t)orow * QPW + 8 * ko) = *(const uint4*)(&qs[w][ch][8 * ko]);
    }
    for (int i = lane; i < 16 * 30; i += 64) {       // v: 16 rows x 30 chunks (NT)
        int ch = i / 30, ko = i % 30;
        __builtin_nontemporal_store(
            *(const u32x4*)((const char*)(&vs[w][ch][0]) + 16 * ko),
            (u32x4*)((char*)(vpad + (size_t)(b * 16 + ch) * QP_PLANE
                             + (size_t)orow * QPW) + 16 * ko));
    }
}

// ---------------- Kernel C: MFMA GEMM (R8/R10 structure: single-buf, 2
// barriers/ry, one-pass LDS-transpose epilogue) + nontemporal Dpart stores ---
__global__ __launch_bounds__(512, 4) void kC(const unsigned short* __restrict__ planes,
                                             const unsigned short* __restrict__ qpadS,
                                             unsigned short* __restrict__ Dpart) {
    int blk = blockIdx.x;
    int b   = blk & 15;
    int nh  = (blk >> 4) & 1;      // N-half: cols [nh*80, nh*80+80)
    int yc  = blk >> 5;            // K-split: yo in [yc*7, yc*7+7)
    int tid = threadIdx.x;
    int w = tid >> 6, lane = tid & 63;
    int tt = lane & 15, kq = lane >> 4;
    int th = tt >> 2, tw = tt & 3;

    __shared__ union {
        uint4 bs[80 * 17];               // B half-tile: 80 n-rows x 136 bf16
        unsigned short dq[80 * 392];     // epilogue transpose: [n][m'=384]+pad
    } sm;

    int nreal = nh ? 67 : 80;            // rows with real data (global n < 147)

    // zero k-pad slots [14,17) for real rows; prefill constant ones rows (nh=1)
    if (tid < nreal * 3) {
        int nl = tid / 3, j2 = tid % 3;
        sm.bs[nl * 17 + 14 + j2] = uint4{0, 0, 0, 0};
    } else if (nh == 1) {
        int t2 = tid - nreal * 3;        // nreal*3 = 201
        if (t2 < 13 * 17) {
            int nl = 67 + t2 / 17, ss = t2 % 17;
            uint4 v = (ss < 14) ? uint4{0x3F803F80u, 0x3F803F80u, 0x3F803F80u, 0x3F803F80u}
                                : uint4{0, 0, 0, 0};
            sm.bs[nl * 17 + ss] = v;
        }
    }

    // staging descriptors: chunk c = tid + 512*i over nreal*14 chunks (16B each)
    int nch = nreal * 14;
    int soff[3];
    int sdst[3];
    bool sact[3];
    #pragma unroll
    for (int i = 0; i < 3; ++i) {
        int c = tid + 512 * i;
        sact[i] = (c < nch);
        int cc2 = sact[i] ? c : 0;
        int nl = cc2 / 14;
        int k0 = (cc2 % 14) * 8;
        int n = nh * 80 + nl;            // global n < 147 guaranteed
        int ci = n / 49;
        int rr = n % 49;
        int dy = rr / 7;
        int dx = rr % 7;
        soff[i] = (((b * 7 + dx) * IN_C + ci) * XPH + dy) * QPW + k0;
        sdst[i] = nl * 17 + (k0 >> 3);
    }

    // A base pointers: single-copy layout, column shift 2*tw (4B aligned)
    const unsigned short* abase[3];
    #pragma unroll
    for (int j = 0; j < 3; ++j) {
        int tile = w * 3 + j;
        int ic = tile >> 3, qc = tile & 7;
        abase[j] = qpadS + (size_t)(b * IN_C + ic) * QP_QSTRIDE + qc * QP_PLANE
                 + (2 * th) * QPW + 2 * tw;
    }

    f32x4 acc[3][5];
    #pragma unroll
    for (int j = 0; j < 3; ++j)
        #pragma unroll
        for (int nt = 0; nt < 5; ++nt)
            acc[j][nt] = f32x4{0.f, 0.f, 0.f, 0.f};

    // prefetch B rows for ry=0
    uint4 pf[3];
    int yo0 = yc * 7;
    #pragma unroll
    for (int i = 0; i < 3; ++i)
        if (sact[i]) pf[i] = *(const uint4*)(planes + soff[i] + yo0 * 240);

    for (int ry = 0; ry < 7; ++ry) {
        int yo = yc * 7 + ry;
        __syncthreads();                       // prev compute done reading LDS
        #pragma unroll
        for (int i = 0; i < 3; ++i)
            if (sact[i]) sm.bs[sdst[i]] = pf[i];
        __syncthreads();
        if (ry < 6) {                          // prefetch next row under compute
            #pragma unroll
            for (int i = 0; i < 3; ++i)
                if (sact[i]) pf[i] = *(const uint4*)(planes + soff[i] + (yo + 1) * 240);
        }
        #pragma unroll
        for (int s = 0; s < 4; ++s) {
            int k = 32 * s + kq * 8;
            int xs = (k < 112) ? k : 96;       // clamped; multiplies B-zeros
            bf16x8 af[3];
            #pragma unroll
            for (int j = 0; j < 3; ++j)
                af[j] = __builtin_bit_cast(bf16x8,
                    ((const uint4_a4*)(abase[j] + yo * QPW + xs))->v);
            #pragma unroll
            for (int nt = 0; nt < 5; ++nt) {
                bf16x8 bf = __builtin_bit_cast(bf16x8, sm.bs[(nt * 16 + tt) * 17 + 4 * s + kq]);
                #pragma unroll
                for (int j = 0; j < 3; ++j)
                    acc[j][nt] = __builtin_amdgcn_mfma_f32_16x16x32_bf16(af[j], bf, acc[j][nt], 0, 0, 0);
            }
        }
    }

    // ---- epilogue: LDS transpose -> coalesced nontemporal streaming stores --
    __syncthreads();                           // done reading sm.bs
    #pragma unroll
    for (int j = 0; j < 3; ++j) {
        int tile = w * 3 + j;
        int mb = tile * 16 + kq * 4;           // m' = ic*128 + qc*16 + kq*4
        #pragma unroll
        for (int nt = 0; nt < 5; ++nt) {
            int nl = nt * 16 + tt;
            u16x4 pk;
            pk.x = f2b(acc[j][nt][0]);
            pk.y = f2b(acc[j][nt][1]);
            pk.z = f2b(acc[j][nt][2]);
            pk.w = f2b(acc[j][nt][3]);
            *(u16x4*)(&sm.dq[nl * 392 + mb]) = pk;
        }
    }
    __syncthreads();
    unsigned short* Dp = Dpart + (size_t)(yc * 16 + b) * (160 * 384);
    for (int c = tid; c < 80 * 48; c += 512) { // 16B chunks: 80 rows x 48
        int nl = c / 48, ms = c % 48;
        __builtin_nontemporal_store(*(const u32x4*)(&sm.dq[nl * 392 + ms * 8]),
                                    (u32x4*)(Dp + (size_t)(nh * 80 + nl) * 384 + ms * 8));
    }
}

// ---------------- Kernel R: reduce 16 bf16 split-K partials -> f32 D --------
__global__ __launch_bounds__(256) void kR(const unsigned short* __restrict__ Dpart,
                                          float* __restrict__ Df) {
    int idx = blockIdx.x * 256 + threadIdx.x;
    float4 s = float4{0.f, 0.f, 0.f, 0.f};
    #pragma unroll
    for (int yc = 0; yc < SPLITS; ++yc) {
        u16x4 v = __builtin_nontemporal_load(
            (const u16x4*)(Dpart + (size_t)yc * D_N + 4 * (size_t)idx));
        s.x += b2f(v.x);
        s.y += b2f(v.y);
        s.z += b2f(v.z);
        s.w += b2f(v.w);
    }
    *(float4*)(Df + 4 * (size_t)idx) = s;   // regular store: kE reads Df next
}

// ---------------- Kernel E: a[v,t] = sum_{qc,r} Wk*D + sum_qc bk*D[147,.] ----
__global__ __launch_bounds__(256) void kE(const float* __restrict__ Df,
                                          const float* __restrict__ Wk,
                                          const float* __restrict__ bk,
                                          float* __restrict__ a_out) {
    int blk = blockIdx.x;
    int bi = blk >> 4;
    int v  = blk & 15;
    int ic = bi % IN_C;
    int b  = bi / IN_C;
    int tid = threadIdx.x;
    int t  = tid & 15;
    int rl = tid >> 4;
    const float* Dbase = Df + (size_t)b * (160 * 384);
    const float* WkI = Wk + (size_t)(ic * V_C + v) * (Q_C * 147);
    const float* bkI = bk + (ic * V_C + v) * Q_C;
    float s = 0.0f;
    for (int qc = 0; qc < Q_C; ++qc) {
        const float* wrow = WkI + qc * 147;
        int mcol = ic * 128 + qc * 16 + t;
        #pragma unroll
        for (int j = 0; j < 10; ++j) {
            int r = rl + 16 * j;
            if (r < 148) {
                float wv = (r < 147) ? wrow[r] : bkI[qc];   // row 147 = ones row
                s = fmaf(wv, Dbase[(size_t)r * 384 + mcol], s);
            }
        }
    }
    __shared__ float red[256];
    red[tid] = s;
    __syncthreads();
    if (tid < 16) {
        float acc2 = 0.f;
        #pragma unroll
        for (int k2 = 0; k2 < 16; ++k2) acc2 += red[k2 * 16 + tid];
        a_out[(size_t)blk * 16 + tid] = acc2;
    }
}

// ---------------- Kernel O: final dynamic conv -> out ----------------
__global__ __launch_bounds__(256) void kO(const float* __restrict__ vpad,
                                          const float* __restrict__ a,
                                          float* __restrict__ out) {
    int idx = blockIdx.x * 256 + threadIdx.x;
    if (idx >= OUT_N) return;
    int ow = idx % 58;
    int t = idx / 58;
    int oh = t % 58; t /= 58;
    int ic = t % IN_C;
    int b  = t / IN_C;
    const float* ab = a + (size_t)(b * IN_C + ic) * (V_C * 16);
    float s = 0.0f;
    for (int vc = 0; vc < V_C; ++vc) {
        const float* vrow = vpad + ((size_t)(b * V_C + vc) * QPH + 2 * oh) * QPW + 2 * ow;
        const float* ar = ab + vc * 16;
        #pragma unroll
        for (int kh = 0; kh < 4; ++kh) {
            float4 xv = ((const float4_a4*)(vrow + kh * QPW))->v;
            s = fmaf(xv.x, ar[kh * 4 + 0], s);
            s = fmaf(xv.y, ar[kh * 4 + 1], s);
            s = fmaf(xv.z, ar[kh * 4 + 2], s);
            s = fmaf(xv.w, ar[kh * 4 + 3], s);
        }
    }
    out[idx] = s;
}

extern "C" void kernel_launch(void* const* d_in, const int* in_sizes, int n_in,
                              void* d_out, int out_size, void* d_ws, size_t ws_size,
                              hipStream_t stream) {
    (void)in_sizes; (void)n_in; (void)out_size; (void)ws_size;
    const float* x  = (const float*)d_in[0];
    const float* Wq = (const float*)d_in[1];
    const float* bq = (const float*)d_in[2];
    const float* Wk = (const float*)d_in[3];
    const float* bk = (const float*)d_in[4];
    const float* Wv = (const float*)d_in[5];
    const float* bv = (const float*)d_in[6];
    float* out = (float*)d_out;

    char* p = (char*)d_ws;
    // region0: pT2 (17.4 MiB, dead after kA) aliased by Dpart (31.5 MiB)
    unsigned short* pT2   = (unsigned short*)p;
    unsigned short* Dpart = (unsigned short*)p;
    p += (size_t)DPART_N * 2;
    unsigned short* planes = (unsigned short*)p;        p += (size_t)PLANES_N * 2;
    float*          vpad   = (float*)p;                 p += (size_t)VPAD_N * 4;
    unsigned short* qpadS  = (unsigned short*)p;        p += (size_t)QPADS_N * 2;
    float*          Df     = (float*)p;                 p += (size_t)D_N * 4;
    unsigned short* Aw2    = (unsigned short*)p;        p += (size_t)AW_N * 2;
    float*          a      = (float*)p;
    // total ~79.6 MiB

    kXT<<<XT_BLOCKS + WZ_BLOCKS, 256, 0, stream>>>(x, planes, pT2,
                                                   Wq, Wv, Aw2, qpadS, vpad);
    kA<<<448, 256, 0, stream>>>(pT2, Aw2, bq, bv, qpadS, vpad);
    kC<<<SPLITS * 2 * 16, 512, 0, stream>>>(planes, qpadS, Dpart);
    kR<<<D_N / 4 / 256, 256, 0, stream>>>(Dpart, Df);
    kE<<<BATCH * IN_C * V_C, 256, 0, stream>>>(Df, Wk, bk, a);
    kO<<<(OUT_N + 255) / 256, 256, 0, stream>>>(vpad, a, out);
}

// Round 15
// 168.467 us; speedup vs baseline: 1.0690x; 1.0690x over previous
//
#include <hip/hip_runtime.h>
#include <hip/hip_bf16.h>

// Problem constants
#define BATCH 16
#define IN_C 3
#define Q_C 8
#define V_C 16
#define HH 224
#define WW 224
#define KK 7

// Padded layouts
#define XPH 230   // stored row = orig row + 3
#define XPW 232
#define QPH 118
#define QPW 120
#define QP_PLANE (QPH*QPW)            // 14160 per (qc)
#define QP_QSTRIDE (Q_C*QP_PLANE)     // 113280 per (b,ic)

// pT2: [b][ci][mb=0..201][kc=0..111][8], element m = 8*mb+j, m=row*7+dx,
// value = x[b,ci,row-3, 2*kc+dx-3]; m >= 1610 zero-padded.
#define PT_MB    202
#define PT2_CHUNKS (BATCH*IN_C*PT_MB*112)      // 1,085,952 16B-chunks
#define PT2_N    ((size_t)PT2_CHUNKS*8)        // 8,687,616 bf16

// Region sizes (elements)
#define PLANES_N (BATCH*7*IN_C*XPH*QPW)        // 9,273,600 bf16
#define VPAD_N   (BATCH*V_C*QPH*QPW)           // 3,624,960 f32
#define QPADS_N  (BATCH*IN_C*QP_QSTRIDE)       // 5,437,440 bf16
#define D_N      (BATCH*160*384)               // [b][n=160][m'=384]
#define SPLITS   16
#define DPART_N  ((size_t)SPLITS*D_N)          // bf16 partials, 31.5 MB
#define OUT_N    (BATCH*IN_C*58*58)
#define AW_N     (4*48*192)                    // 4 phase-shifted weight mats

// WZ tail-work partition (fused into kXT)
#define ZQ_CHUNKS (BATCH*IN_C*Q_C*6*15)        // 34560 uint4 (q planes, 6 border rows)
#define ZV_CHUNKS (BATCH*V_C*6*30)             // 46080 uint4 (v planes, 6 border rows)
#define WZ_TOTAL  (AW_N + ZQ_CHUNKS + ZV_CHUNKS)   // 117504
#define XT_BLOCKS (BATCH*IN_C*29)              // 1392
#define WZ_BLOCKS ((WZ_TOTAL + 255) / 256)     // 459

typedef __attribute__((ext_vector_type(8))) short bf16x8;
typedef __attribute__((ext_vector_type(4))) float f32x4;
typedef __attribute__((ext_vector_type(4))) unsigned short u16x4;
typedef __attribute__((ext_vector_type(4))) unsigned int u32x4;   // native vec for nontemporal builtins

struct __attribute__((packed, aligned(4))) uint4_a4 { uint4 v; };
struct __attribute__((packed, aligned(4))) float4_a4 { float4 v; };

static __device__ inline unsigned short f2b(float f) {
    __hip_bfloat16 h = __float2bfloat16(f);
    return *reinterpret_cast<unsigned short*>(&h);
}
static __device__ inline float b2f(unsigned short u) {
    unsigned int v = ((unsigned int)u) << 16;
    return __builtin_bit_cast(float, v);
}
static __device__ inline bf16x8 ld16(const unsigned short* p) {
    return __builtin_bit_cast(bf16x8, *(const uint4*)p);
}

// ---------------- Kernel XT: fused planes + pT2 builder + WZ tail -----------
__global__ __launch_bounds__(256) void kXT(const float* __restrict__ x,
                                           unsigned short* __restrict__ planes,
                                           unsigned short* __restrict__ pT2,
                                           const float* __restrict__ Wq,
                                           const float* __restrict__ Wv,
                                           unsigned short* __restrict__ Aw2,
                                           unsigned short* __restrict__ qpadS,
                                           float* __restrict__ vpad) {
    int blk = blockIdx.x;
    int tid = threadIdx.x;

    if (blk >= XT_BLOCKS) {
        // ---- WZ tail work ----
        int idx = (blk - XT_BLOCKS) * 256 + tid;
        if (idx >= WZ_TOTAL) return;
        if (idx < AW_N) {
            int n = idx % 192;
            int t3 = idx / 192;
            int ch = t3 % 48;
            int p4 = t3 / 48;
            int ci = n / 64;
            int t  = (n % 64) - 2 * p4;
            float v = 0.0f;
            if (ch < 40 && t >= 0 && t < 49) {
                int k = ci * 49 + t;
                v = (ch < 24) ? Wq[(size_t)ch * 147 + k] : Wv[(size_t)(ch - 24) * 147 + k];
            }
            Aw2[idx] = f2b(v);
            return;
        }
        uint4 z = uint4{0, 0, 0, 0};
        int j = idx - AW_N;
        if (j < ZQ_CHUNKS) {
            int ko = j % 15;
            int t2 = j / 15;
            int r6 = t2 % 6;
            int plane = t2 / 6;
            int row = (r6 < 3) ? r6 : (112 + r6);   // 0,1,2,115,116,117
            *(uint4*)(qpadS + (size_t)plane * QP_PLANE + (size_t)row * QPW + 8 * ko) = z;
        } else {
            int j2 = j - ZQ_CHUNKS;
            int ko = j2 % 30;
            int t2 = j2 / 30;
            int r6 = t2 % 6;
            int plane = t2 / 6;
            int row = (r6 < 3) ? r6 : (112 + r6);
            *(uint4*)((char*)(vpad + (size_t)plane * QP_PLANE + (size_t)row * QPW) + 16 * ko) = z;
        }
        return;
    }

    // ---- stripe work: blk = b*87 + ci*29 + r0 ----
    int r0 = blk % 29;
    int t0 = blk / 29;
    int ci = t0 % IN_C;
    int b  = t0 / IN_C;

    __shared__ unsigned short xl[8][240];   // LDS col c = orig col c-3

    const float* xb = x + (size_t)(b * IN_C + ci) * (HH * WW);
    for (int idx = tid; idx < 8 * 240; idx += 256) {
        int row8 = idx / 240, c = idx % 240;
        int r = 8 * r0 + row8 - 3;          // orig row
        int cc = c - 3;                     // orig col
        float val = 0.0f;
        if (r >= 0 && r < HH && cc >= 0 && cc < WW)
            val = xb[(size_t)r * WW + cc];
        xl[row8][c] = f2b(val);
    }
    __syncthreads();

    // Phase A: planes[b][dx][ci][prow][k], FULL rows: 15 uint4 chunks
    for (int t2 = tid; t2 < 840; t2 += 256) {
        int ko = t2 % 15;
        int t3 = t2 / 15;
        int row8 = t3 % 8;
        int dx = t3 / 8;
        int prow = 8 * r0 + row8;
        if (prow >= XPH) continue;
        unsigned short pk[8];
        if (ko < 14) {
            #pragma unroll
            for (int j = 0; j < 8; ++j)
                pk[j] = xl[row8][16 * ko + 2 * j + dx];
        } else {
            #pragma unroll
            for (int j = 0; j < 8; ++j) pk[j] = 0;   // pad cols [112,120)
        }
        unsigned short* dst = planes
            + ((size_t)((b * 7 + dx) * IN_C + ci) * XPH + prow) * QPW + 8 * ko;
        *(uint4*)dst = *(const uint4*)pk;
    }

    // Phase B: pT2[b][ci][mb][kc][8]; mb = 7*r0 + mbr; m = 8*mb+j = row*7+dx
    for (int t2 = tid; t2 < 784; t2 += 256) {
        int kc  = t2 % 112;
        int mbr = t2 / 112;
        int mb = 7 * r0 + mbr;
        if (mb >= PT_MB) continue;
        unsigned short pk[8];
        #pragma unroll
        for (int j = 0; j < 8; ++j) {
            int mrel = 8 * mbr + j;          // in [0,56): row8 = mrel/7
            int row8 = mrel / 7;
            int dxm  = mrel - 7 * row8;
            pk[j] = xl[row8][2 * kc + dxm];  // rows >=230 already zero in LDS
        }
        unsigned short* dst = pT2 + ((size_t)((b * IN_C + ci) * PT_MB + mb) * 112 + kc) * 8;
        *(uint4*)dst = *(const uint4*)pk;
    }
}

// ---------------- Kernel A: MFMA q+v conv, LDS-staged full-row epilogue -----
__global__ __launch_bounds__(256) void kA(const unsigned short* __restrict__ pT2,
                                          const unsigned short* __restrict__ Aw2,
                                          const float* __restrict__ bq,
                                          const float* __restrict__ bv,
                                          unsigned short* __restrict__ qpadS,
                                          float* __restrict__ vpad) {
    int g = blockIdx.x;                 // 448 blocks; XCD swizzle: b tracks g&7
    int r8 = g & 7, q8 = g >> 3;
    int b  = r8 + 8 * (q8 / 28);
    int yq = q8 % 28;
    int w  = threadIdx.x >> 6;
    int yo = yq * 4 + w;                // [0,112)
    int lane = threadIdx.x & 63;
    int cl = lane & 15, kq = lane >> 4;

    __shared__ unsigned short qs[4][24][120];   // per-wave q rows (full 120)
    __shared__ float          vs[4][16][120];   // per-wave v rows

    int m14 = 14 * yo;
    int p4  = (m14 >> 1) & 3;           // (14yo mod 8)/2
    int ms8 = m14 >> 3;                 // aligned m-block start

    const unsigned short* AwP = Aw2 + (size_t)p4 * (48 * 192);
    bf16x8 af[3][6];
    #pragma unroll
    for (int mt = 0; mt < 3; ++mt)
        #pragma unroll
        for (int s = 0; s < 6; ++s)
            af[mt][s] = ld16(AwP + (size_t)(mt * 16 + cl) * 192 + s * 32 + kq * 8);

    f32x4 acc[3][7];
    #pragma unroll
    for (int mt = 0; mt < 3; ++mt)
        #pragma unroll
        for (int nt = 0; nt < 7; ++nt)
            acc[mt][nt] = f32x4{0.f, 0.f, 0.f, 0.f};

    #pragma unroll
    for (int s = 0; s < 6; ++s) {
        int ci = s >> 1;
        int mb = ms8 + kq + 4 * (s & 1);
        const unsigned short* bp = pT2
            + ((size_t)((b * IN_C + ci) * PT_MB + mb) * 112) * 8;
        bf16x8 bfr[7];
        #pragma unroll
        for (int nt = 0; nt < 7; ++nt)
            bfr[nt] = ld16(bp + (size_t)(nt * 16 + cl) * 8);
        #pragma unroll
        for (int nt = 0; nt < 7; ++nt)
            #pragma unroll
            for (int mt = 0; mt < 3; ++mt)
                acc[mt][nt] = __builtin_amdgcn_mfma_f32_16x16x32_bf16(af[mt][s], bfr[nt], acc[mt][nt], 0, 0, 0);
    }

    float bias[3][4];
    #pragma unroll
    for (int mt = 0; mt < 3; ++mt)
        #pragma unroll
        for (int r = 0; r < 4; ++r) {
            int ch = mt * 16 + kq * 4 + r;
            bias[mt][r] = (ch < 24) ? bq[ch] : (ch < 40 ? bv[ch - 24] : 0.0f);
        }

    // zero the col pads (0..2, 115..119) of this wave's LDS rows
    for (int i = lane; i < 24 * 8; i += 64) {
        int ch = i / 8, c = i % 8;
        qs[w][ch][(c < 3) ? c : (112 + c)] = 0;
    }
    for (int i = lane; i < 16 * 8; i += 64) {
        int ch = i / 8, c = i % 8;
        vs[w][ch][(c < 3) ? c : (112 + c)] = 0.0f;
    }

    // scatter acc -> LDS rows
    #pragma unroll
    for (int mt = 0; mt < 3; ++mt) {
        #pragma unroll
        for (int nt = 0; nt < 7; ++nt) {
            int kc = nt * 16 + cl;
            #pragma unroll
            for (int r = 0; r < 4; ++r) {
                int ch = mt * 16 + kq * 4 + r;
                float val = acc[mt][nt][r] + bias[mt][r];
                if (ch < 24) qs[w][ch][3 + kc] = f2b(val);
                else if (ch < 40) vs[w][ch - 24][3 + kc] = val;
            }
        }
    }
    __syncthreads();

    // coalesced full-row stores
    int orow = yo + 3;
    for (int i = lane; i < 24 * 15; i += 64) {       // q: 24 rows x 15 uint4
        int ch = i / 15, ko = i % 15;
        int icq = ch >> 3, qc = ch & 7;
        *(uint4*)(qpadS + (size_t)((b * 3 + icq) * 8 + qc) * QP_PLANE
                  + (size_t)orow * QPW + 8 * ko) = *(const uint4*)(&qs[w][ch][8 * ko]);
    }
    for (int i = lane; i < 16 * 30; i += 64) {       // v: 16 rows x 30 float4
        int ch = i / 30, ko = i % 30;
        *(float4*)((char*)(vpad + (size_t)(b * 16 + ch) * QP_PLANE
                           + (size_t)orow * QPW) + 16 * ko) =
            *(const float4*)((const char*)(&vs[w][ch][0]) + 16 * ko);
    }
}

// ---------------- Kernel C: MFMA GEMM (R8/R10 structure: single-buf, 2
// barriers/ry, one-pass LDS-transpose epilogue) + nontemporal Dpart stores ---
__global__ __launch_bounds__(512, 4) void kC(const unsigned short* __restrict__ planes,
                                             const unsigned short* __restrict__ qpadS,
                                             unsigned short* __restrict__ Dpart) {
    int blk = blockIdx.x;
    int b   = blk & 15;
    int nh  = (blk >> 4) & 1;      // N-half: cols [nh*80, nh*80+80)
    int yc  = blk >> 5;            // K-split: yo in [yc*7, yc*7+7)
    int tid = threadIdx.x;
    int w = tid >> 6, lane = tid & 63;
    int tt = lane & 15, kq = lane >> 4;
    int th = tt >> 2, tw = tt & 3;

    __shared__ union {
        uint4 bs[80 * 17];               // B half-tile: 80 n-rows x 136 bf16
        unsigned short dq[80 * 392];     // epilogue transpose: [n][m'=384]+pad
    } sm;

    int nreal = nh ? 67 : 80;            // rows with real data (global n < 147)

    // zero k-pad slots [14,17) for real rows; prefill constant ones rows (nh=1)
    if (tid < nreal * 3) {
        int nl = tid / 3, j2 = tid % 3;
        sm.bs[nl * 17 + 14 + j2] = uint4{0, 0, 0, 0};
    } else if (nh == 1) {
        int t2 = tid - nreal * 3;        // nreal*3 = 201
        if (t2 < 13 * 17) {
            int nl = 67 + t2 / 17, ss = t2 % 17;
            uint4 v = (ss < 14) ? uint4{0x3F803F80u, 0x3F803F80u, 0x3F803F80u, 0x3F803F80u}
                                : uint4{0, 0, 0, 0};
            sm.bs[nl * 17 + ss] = v;
        }
    }

    // staging descriptors: chunk c = tid + 512*i over nreal*14 chunks (16B each)
    int nch = nreal * 14;
    int soff[3];
    int sdst[3];
    bool sact[3];
    #pragma unroll
    for (int i = 0; i < 3; ++i) {
        int c = tid + 512 * i;
        sact[i] = (c < nch);
        int cc2 = sact[i] ? c : 0;
        int nl = cc2 / 14;
        int k0 = (cc2 % 14) * 8;
        int n = nh * 80 + nl;            // global n < 147 guaranteed
        int ci = n / 49;
        int rr = n % 49;
        int dy = rr / 7;
        int dx = rr % 7;
        soff[i] = (((b * 7 + dx) * IN_C + ci) * XPH + dy) * QPW + k0;
        sdst[i] = nl * 17 + (k0 >> 3);
    }

    // A base pointers: single-copy layout, column shift 2*tw (4B aligned)
    const unsigned short* abase[3];
    #pragma unroll
    for (int j = 0; j < 3; ++j) {
        int tile = w * 3 + j;
        int ic = tile >> 3, qc = tile & 7;
        abase[j] = qpadS + (size_t)(b * IN_C + ic) * QP_QSTRIDE + qc * QP_PLANE
                 + (2 * th) * QPW + 2 * tw;
    }

    f32x4 acc[3][5];
    #pragma unroll
    for (int j = 0; j < 3; ++j)
        #pragma unroll
        for (int nt = 0; nt < 5; ++nt)
            acc[j][nt] = f32x4{0.f, 0.f, 0.f, 0.f};

    // prefetch B rows for ry=0
    uint4 pf[3];
    int yo0 = yc * 7;
    #pragma unroll
    for (int i = 0; i < 3; ++i)
        if (sact[i]) pf[i] = *(const uint4*)(planes + soff[i] + yo0 * 240);

    for (int ry = 0; ry < 7; ++ry) {
        int yo = yc * 7 + ry;
        __syncthreads();                       // prev compute done reading LDS
        #pragma unroll
        for (int i = 0; i < 3; ++i)
            if (sact[i]) sm.bs[sdst[i]] = pf[i];
        __syncthreads();
        if (ry < 6) {                          // prefetch next row under compute
            #pragma unroll
            for (int i = 0; i < 3; ++i)
                if (sact[i]) pf[i] = *(const uint4*)(planes + soff[i] + (yo + 1) * 240);
        }
        #pragma unroll
        for (int s = 0; s < 4; ++s) {
            int k = 32 * s + kq * 8;
            int xs = (k < 112) ? k : 96;       // clamped; multiplies B-zeros
            bf16x8 af[3];
            #pragma unroll
            for (int j = 0; j < 3; ++j)
                af[j] = __builtin_bit_cast(bf16x8,
                    ((const uint4_a4*)(abase[j] + yo * QPW + xs))->v);
            #pragma unroll
            for (int nt = 0; nt < 5; ++nt) {
                bf16x8 bf = __builtin_bit_cast(bf16x8, sm.bs[(nt * 16 + tt) * 17 + 4 * s + kq]);
                #pragma unroll
                for (int j = 0; j < 3; ++j)
                    acc[j][nt] = __builtin_amdgcn_mfma_f32_16x16x32_bf16(af[j], bf, acc[j][nt], 0, 0, 0);
            }
        }
    }

    // ---- epilogue: LDS transpose -> coalesced nontemporal streaming stores --
    __syncthreads();                           // done reading sm.bs
    #pragma unroll
    for (int j = 0; j < 3; ++j) {
        int tile = w * 3 + j;
        int mb = tile * 16 + kq * 4;           // m' = ic*128 + qc*16 + kq*4
        #pragma unroll
        for (int nt = 0; nt < 5; ++nt) {
            int nl = nt * 16 + tt;
            u16x4 pk;
            pk.x = f2b(acc[j][nt][0]);
            pk.y = f2b(acc[j][nt][1]);
            pk.z = f2b(acc[j][nt][2]);
            pk.w = f2b(acc[j][nt][3]);
            *(u16x4*)(&sm.dq[nl * 392 + mb]) = pk;
        }
    }
    __syncthreads();
    unsigned short* Dp = Dpart + (size_t)(yc * 16 + b) * (160 * 384);
    for (int c = tid; c < 80 * 48; c += 512) { // 16B chunks: 80 rows x 48
        int nl = c / 48, ms = c % 48;
        __builtin_nontemporal_store(*(const u32x4*)(&sm.dq[nl * 392 + ms * 8]),
                                    (u32x4*)(Dp + (size_t)(nh * 80 + nl) * 384 + ms * 8));
    }
}

// ---------------- Kernel R: reduce 16 bf16 split-K partials -> f32 D --------
__global__ __launch_bounds__(256) void kR(const unsigned short* __restrict__ Dpart,
                                          float* __restrict__ Df) {
    int idx = blockIdx.x * 256 + threadIdx.x;
    float4 s = float4{0.f, 0.f, 0.f, 0.f};
    #pragma unroll
    for (int yc = 0; yc < SPLITS; ++yc) {
        u16x4 v = __builtin_nontemporal_load(
            (const u16x4*)(Dpart + (size_t)yc * D_N + 4 * (size_t)idx));
        s.x += b2f(v.x);
        s.y += b2f(v.y);
        s.z += b2f(v.z);
        s.w += b2f(v.w);
    }
    *(float4*)(Df + 4 * (size_t)idx) = s;   // regular store: kE reads Df next
}

// ---------------- Kernel E: a[v,t] = sum_{qc,r} Wk*D + sum_qc bk*D[147,.] ----
__global__ __launch_bounds__(256) void kE(const float* __restrict__ Df,
                                          const float* __restrict__ Wk,
                                          const float* __restrict__ bk,
                                          float* __restrict__ a_out) {
    int blk = blockIdx.x;
    int bi = blk >> 4;
    int v  = blk & 15;
    int ic = bi % IN_C;
    int b  = bi / IN_C;
    int tid = threadIdx.x;
    int t  = tid & 15;
    int rl = tid >> 4;
    const float* Dbase = Df + (size_t)b * (160 * 384);
    const float* WkI = Wk + (size_t)(ic * V_C + v) * (Q_C * 147);
    const float* bkI = bk + (ic * V_C + v) * Q_C;
    float s = 0.0f;
    for (int qc = 0; qc < Q_C; ++qc) {
        const float* wrow = WkI + qc * 147;
        int mcol = ic * 128 + qc * 16 + t;
        #pragma unroll
        for (int j = 0; j < 10; ++j) {
            int r = rl + 16 * j;
            if (r < 148) {
                float wv = (r < 147) ? wrow[r] : bkI[qc];   // row 147 = ones row
                s = fmaf(wv, Dbase[(size_t)r * 384 + mcol], s);
            }
        }
    }
    __shared__ float red[256];
    red[tid] = s;
    __syncthreads();
    if (tid < 16) {
        float acc2 = 0.f;
        #pragma unroll
        for (int k2 = 0; k2 < 16; ++k2) acc2 += red[k2 * 16 + tid];
        a_out[(size_t)blk * 16 + tid] = acc2;
    }
}

// ---------------- Kernel O: final dynamic conv -> out ----------------
__global__ __launch_bounds__(256) void kO(const float* __restrict__ vpad,
                                          const float* __restrict__ a,
                                          float* __restrict__ out) {
    int idx = blockIdx.x * 256 + threadIdx.x;
    if (idx >= OUT_N) return;
    int ow = idx % 58;
    int t = idx / 58;
    int oh = t % 58; t /= 58;
    int ic = t % IN_C;
    int b  = t / IN_C;
    const float* ab = a + (size_t)(b * IN_C + ic) * (V_C * 16);
    float s = 0.0f;
    for (int vc = 0; vc < V_C; ++vc) {
        const float* vrow = vpad + ((size_t)(b * V_C + vc) * QPH + 2 * oh) * QPW + 2 * ow;
        const float* ar = ab + vc * 16;
        #pragma unroll
        for (int kh = 0; kh < 4; ++kh) {
            float4 xv = ((const float4_a4*)(vrow + kh * QPW))->v;
            s = fmaf(xv.x, ar[kh * 4 + 0], s);
            s = fmaf(xv.y, ar[kh * 4 + 1], s);
            s = fmaf(xv.z, ar[kh * 4 + 2], s);
            s = fmaf(xv.w, ar[kh * 4 + 3], s);
        }
    }
    out[idx] = s;
}

extern "C" void kernel_launch(void* const* d_in, const int* in_sizes, int n_in,
                              void* d_out, int out_size, void* d_ws, size_t ws_size,
                              hipStream_t stream) {
    (void)in_sizes; (void)n_in; (void)out_size; (void)ws_size;
    const float* x  = (const float*)d_in[0];
    const float* Wq = (const float*)d_in[1];
    const float* bq = (const float*)d_in[2];
    const float* Wk = (const float*)d_in[3];
    const float* bk = (const float*)d_in[4];
    const float* Wv = (const float*)d_in[5];
    const float* bv = (const float*)d_in[6];
    float* out = (float*)d_out;

    char* p = (char*)d_ws;
    // region0: pT2 (17.4 MiB, dead after kA) aliased by Dpart (31.5 MiB)
    unsigned short* pT2   = (unsigned short*)p;
    unsigned short* Dpart = (unsigned short*)p;
    p += (size_t)DPART_N * 2;
    unsigned short* planes = (unsigned short*)p;        p += (size_t)PLANES_N * 2;
    float*          vpad   = (float*)p;                 p += (size_t)VPAD_N * 4;
    unsigned short* qpadS  = (unsigned short*)p;        p += (size_t)QPADS_N * 2;
    float*          Df     = (float*)p;                 p += (size_t)D_N * 4;
    unsigned short* Aw2    = (unsigned short*)p;        p += (size_t)AW_N * 2;
    float*          a      = (float*)p;
    // total ~79.6 MiB

    kXT<<<XT_BLOCKS + WZ_BLOCKS, 256, 0, stream>>>(x, planes, pT2,
                                                   Wq, Wv, Aw2, qpadS, vpad);
    kA<<<448, 256, 0, stream>>>(pT2, Aw2, bq, bv, qpadS, vpad);
    kC<<<SPLITS * 2 * 16, 512, 0, stream>>>(planes, qpadS, Dpart);
    kR<<<D_N / 4 / 256, 256, 0, stream>>>(Dpart, Df);
    kE<<<BATCH * IN_C * V_C, 256, 0, stream>>>(Df, Wk, bk, a);
    kO<<<(OUT_N + 255) / 256, 256, 0, stream>>>(vpad, a, out);
}